// Round 1
// baseline (624.483 us; speedup 1.0000x reference)
//
#include <hip/hip_runtime.h>
#include <hip/hip_bf16.h>
#include <stdint.h>

typedef __hip_bfloat16 bf16;
typedef __attribute__((ext_vector_type(8))) short short8;
typedef __attribute__((ext_vector_type(4))) float floatx4;

#define E_DIM 1024
#define S_LEN 2048
#define NB    2
#define NH    16
#define HD    64
#define FFN   4096
#define MTOT  4096   // NB * S_LEN

// ---- async global->LDS, 16B per lane (wave-uniform LDS base + lane*16) ----
__device__ __forceinline__ void gl_lds16(const void* g, void* l) {
  __builtin_amdgcn_global_load_lds(
      (__attribute__((address_space(1))) void*)(g),
      (__attribute__((address_space(3))) void*)(l), 16, 0, 0);
}

// ---------------------------------------------------------------------------
// fp32 -> bf16 convert (4 elems/thread)
// ---------------------------------------------------------------------------
__global__ __launch_bounds__(256)
void cvt_bf16(const float* __restrict__ in, bf16* __restrict__ out) {
  const size_t i = ((size_t)blockIdx.x * 256 + threadIdx.x) * 4;
  float4 v = *(const float4*)(in + i);
  out[i + 0] = __float2bfloat16(v.x);
  out[i + 1] = __float2bfloat16(v.y);
  out[i + 2] = __float2bfloat16(v.z);
  out[i + 3] = __float2bfloat16(v.w);
}

// ---------------------------------------------------------------------------
// transpose + convert: in (R,C) fp32 row-major -> out (C,R) bf16 row-major
// ---------------------------------------------------------------------------
__global__ __launch_bounds__(256)
void transpose_cvt(const float* __restrict__ in, bf16* __restrict__ out,
                   int R, int C) {
  __shared__ float tile[32][33];
  const int tx = threadIdx.x & 31;
  const int ty = threadIdx.x >> 5;      // 0..7
  const int c0 = blockIdx.x * 32;
  const int r0 = blockIdx.y * 32;
#pragma unroll
  for (int j = 0; j < 32; j += 8)
    tile[ty + j][tx] = in[(size_t)(r0 + ty + j) * C + c0 + tx];
  __syncthreads();
#pragma unroll
  for (int j = 0; j < 32; j += 8)
    out[(size_t)(c0 + ty + j) * R + r0 + tx] = __float2bfloat16(tile[tx][ty + j]);
}

// ---------------------------------------------------------------------------
// GEMM: C(M,N) = A(M,K) @ B^T  where B is stored (N,K) row-major, both bf16.
// 128x128 tile, BK=32, 4 waves x (64x64), 16x16x32 bf16 MFMA,
// global_load_lds width-16 staging (m97 structure).
// mode 0: fp32 row-major store (+bias)
// mode 1: ReLU + bf16 row-major store (+bias)
// mode 2: bf16 scatter to (B*H, S, D) QKV layout (+bias)
// ---------------------------------------------------------------------------
__global__ __launch_bounds__(256)
void gemm_bt(const bf16* __restrict__ A, const bf16* __restrict__ B,
             const float* __restrict__ bias, void* __restrict__ Cout,
             int M, int N, int K, int mode) {
  __shared__ alignas(16) bf16 sA[128 * 32];
  __shared__ alignas(16) bf16 sB[128 * 32];
  const int tid   = threadIdx.x;
  const int wave  = tid >> 6;
  const int lane  = tid & 63;
  const int row16 = lane & 15;
  const int quad  = lane >> 4;
  const int m0 = blockIdx.x * 128;
  const int n0 = blockIdx.y * 128;
  const int wm = (wave >> 1) * 64;
  const int wn = (wave & 1) * 64;

  floatx4 acc[4][4];
#pragma unroll
  for (int i = 0; i < 4; i++)
#pragma unroll
    for (int j = 0; j < 4; j++) {
      floatx4 z = {0.f, 0.f, 0.f, 0.f};
      acc[i][j] = z;
    }

  for (int k0 = 0; k0 < K; k0 += 32) {
    // stage A and B tiles: 8 chunks each, chunk = 64 lanes * 16B = 512 elems
#pragma unroll
    for (int j = 0; j < 2; ++j) {
      const int chunk = wave * 2 + j;
      const int e = chunk * 512 + lane * 8;
      const int r = e >> 5;        // tile row
      const int kk = e & 31;       // tile k
      gl_lds16(A + (size_t)(m0 + r) * K + k0 + kk, sA + chunk * 512);
      gl_lds16(B + (size_t)(n0 + r) * K + k0 + kk, sB + chunk * 512);
    }
    __syncthreads();

    short8 af[4], bfr[4];
#pragma unroll
    for (int i = 0; i < 4; i++) {
      af[i]  = *(const short8*)(sA + (wm + i * 16 + row16) * 32 + quad * 8);
      bfr[i] = *(const short8*)(sB + (wn + i * 16 + row16) * 32 + quad * 8);
    }
#pragma unroll
    for (int mi = 0; mi < 4; mi++)
#pragma unroll
      for (int ni = 0; ni < 4; ni++)
        acc[mi][ni] = __builtin_amdgcn_mfma_f32_16x16x32_bf16(
            af[mi], bfr[ni], acc[mi][ni], 0, 0, 0);
    __syncthreads();
  }

  float bval[4];
#pragma unroll
  for (int ni = 0; ni < 4; ni++) bval[ni] = bias[n0 + wn + ni * 16 + row16];

#pragma unroll
  for (int mi = 0; mi < 4; mi++) {
#pragma unroll
    for (int ni = 0; ni < 4; ni++) {
      const int col = n0 + wn + ni * 16 + row16;
#pragma unroll
      for (int r = 0; r < 4; r++) {
        const int row = m0 + wm + mi * 16 + quad * 4 + r;
        float v = acc[mi][ni][r] + bval[ni];
        if (mode == 0) {
          ((float*)Cout)[(size_t)row * N + col] = v;
        } else if (mode == 1) {
          v = v > 0.f ? v : 0.f;
          ((bf16*)Cout)[(size_t)row * N + col] = __float2bfloat16(v);
        } else {
          const int b = row >> 11, s = row & 2047;     // row = b*2048+s
          const int h = col >> 6,  d = col & 63;       // col = h*64+d
          ((bf16*)Cout)[(((size_t)(b * NH + h)) * S_LEN + s) * HD + d] =
              __float2bfloat16(v);
        }
      }
    }
  }
}

// ---------------------------------------------------------------------------
// Flash attention: one block per (bh, 64-query tile). D=64, K-tile=64.
// Q,K,V: (B*H, S, D) bf16.  Out: (B, S, E) bf16 (heads merged).
// ---------------------------------------------------------------------------
__global__ __launch_bounds__(256)
void flash_attn(const bf16* __restrict__ Q, const bf16* __restrict__ K,
                const bf16* __restrict__ V, const float* __restrict__ mask,
                bf16* __restrict__ Out) {
  __shared__ alignas(16) bf16 sK[64 * 64];   // [key][d]
  __shared__ alignas(16) bf16 sVt[64 * 64];  // [d][key]
  __shared__ alignas(16) bf16 sP[4][16 * 64];

  const int tid   = threadIdx.x;
  const int wave  = tid >> 6;
  const int lane  = tid & 63;
  const int row16 = lane & 15;
  const int quad  = lane >> 4;
  const int bh = blockIdx.y;
  const int b = bh >> 4, h = bh & 15;
  const int q0 = blockIdx.x * 64;

  const size_t headoff = (size_t)bh * S_LEN * HD;

  // Q fragments: wave handles query rows [q0+wave*16, +16)
  const bf16* qrow = Q + headoff + (size_t)(q0 + wave * 16 + row16) * HD;
  short8 qf[2];
  qf[0] = *(const short8*)(qrow + quad * 8);
  qf[1] = *(const short8*)(qrow + 32 + quad * 8);

  float m_r[4], l_r[4];
  floatx4 ov[4];
#pragma unroll
  for (int i = 0; i < 4; i++) {
    m_r[i] = -1e30f;
    l_r[i] = 0.f;
    floatx4 z = {0.f, 0.f, 0.f, 0.f};
    ov[i] = z;
  }

  for (int kt = 0; kt < S_LEN / 64; ++kt) {
    const bf16* Kt = K + headoff + (size_t)kt * 64 * HD;
    const bf16* Vg = V + headoff + (size_t)kt * 64 * HD;
    // stage K tile (row-major [key][d]) via global_load_lds
#pragma unroll
    for (int j = 0; j < 2; ++j) {
      const int chunk = wave * 2 + j;
      const int e = chunk * 512 + lane * 8;
      gl_lds16(Kt + e, sK + chunk * 512);
    }
    // stage V transposed: sVt[d][key]
#pragma unroll
    for (int j = 0; j < 2; ++j) {
      const int c2 = tid + j * 256;            // 0..511
      const int key = c2 >> 3, d0 = (c2 & 7) * 8;
      short8 vv = *(const short8*)(Vg + (size_t)key * HD + d0);
#pragma unroll
      for (int i = 0; i < 8; i++)
        ((short*)sVt)[(d0 + i) * 64 + key] = vv[i];
    }
    __syncthreads();

    // scores: S = Q . K^T  (16 q-rows x 64 keys per wave)
    floatx4 sc[4];
#pragma unroll
    for (int ni = 0; ni < 4; ni++) {
      floatx4 z = {0.f, 0.f, 0.f, 0.f};
      sc[ni] = z;
    }
#pragma unroll
    for (int ks = 0; ks < 2; ks++)
#pragma unroll
      for (int ni = 0; ni < 4; ni++) {
        short8 kf = *(const short8*)(sK + (ni * 16 + row16) * 64 + ks * 32 + quad * 8);
        sc[ni] = __builtin_amdgcn_mfma_f32_16x16x32_bf16(qf[ks], kf, sc[ni], 0, 0, 0);
      }

    // scale + mask
    float mv[4];
#pragma unroll
    for (int ni = 0; ni < 4; ni++)
      mv[ni] = -1e12f * mask[(size_t)b * S_LEN + kt * 64 + ni * 16 + row16];
#pragma unroll
    for (int ni = 0; ni < 4; ni++)
#pragma unroll
      for (int r = 0; r < 4; r++) sc[ni][r] = sc[ni][r] * 0.125f + mv[ni];

    // row max (online softmax)
    float m_new[4], alpha[4], tsum[4];
#pragma unroll
    for (int r = 0; r < 4; r++) {
      float t = fmaxf(fmaxf(sc[0][r], sc[1][r]), fmaxf(sc[2][r], sc[3][r]));
#pragma unroll
      for (int d = 1; d < 16; d <<= 1) t = fmaxf(t, __shfl_xor(t, d));
      m_new[r] = fmaxf(m_r[r], t);
      alpha[r] = __expf(m_r[r] - m_new[r]);
      m_r[r] = m_new[r];
      tsum[r] = 0.f;
    }
#pragma unroll
    for (int ni = 0; ni < 4; ni++)
#pragma unroll
      for (int r = 0; r < 4; r++) {
        float p = __expf(sc[ni][r] - m_r[r]);
        sc[ni][r] = p;
        tsum[r] += p;
      }
#pragma unroll
    for (int r = 0; r < 4; r++) {
#pragma unroll
      for (int d = 1; d < 16; d <<= 1) tsum[r] += __shfl_xor(tsum[r], d);
      l_r[r] = l_r[r] * alpha[r] + tsum[r];
    }

    // P strip -> LDS (C/D layout -> A-operand layout round-trip)
    short* sPw = (short*)sP[wave];
#pragma unroll
    for (int ni = 0; ni < 4; ni++)
#pragma unroll
      for (int r = 0; r < 4; r++) {
        bf16 pb = __float2bfloat16(sc[ni][r]);
        sPw[(quad * 4 + r) * 64 + ni * 16 + row16] = *(short*)&pb;
      }

    // rescale O
#pragma unroll
    for (int ni = 0; ni < 4; ni++)
#pragma unroll
      for (int r = 0; r < 4; r++) ov[ni][r] *= alpha[r];

    // O += P . V
#pragma unroll
    for (int ks = 0; ks < 2; ks++) {
      short8 pf = *(const short8*)(sPw + row16 * 64 + ks * 32 + quad * 8);
#pragma unroll
      for (int ni = 0; ni < 4; ni++) {
        short8 vf = *(const short8*)((short*)sVt + (ni * 16 + row16) * 64 + ks * 32 + quad * 8);
        ov[ni] = __builtin_amdgcn_mfma_f32_16x16x32_bf16(pf, vf, ov[ni], 0, 0, 0);
      }
    }
    __syncthreads();
  }

  // epilogue: out[b][q][h*64+d], heads merged
#pragma unroll
  for (int ni = 0; ni < 4; ni++) {
    const int d = ni * 16 + row16;
#pragma unroll
    for (int r = 0; r < 4; r++) {
      const int q = q0 + wave * 16 + quad * 4 + r;
      float v = ov[ni][r] / l_r[r];
      Out[((size_t)(b * S_LEN + q)) * E_DIM + h * HD + d] = __float2bfloat16(v);
    }
  }
}

// ---------------------------------------------------------------------------
// Fused residual + LayerNorm. One block per row (1024 cols, 4/thread).
// out = (A+Bres - mu)*rsqrt(var+eps)*g + be ; optional bf16 copy.
// ---------------------------------------------------------------------------
__global__ __launch_bounds__(256)
void ln_fused(const float* __restrict__ A, const float* __restrict__ Bres,
              const float* __restrict__ g, const float* __restrict__ be,
              float* __restrict__ outf, bf16* __restrict__ outb) {
  const int row = blockIdx.x;
  const int tid = threadIdx.x;
  const size_t base = (size_t)row * 1024;
  float4 a = *(const float4*)(A + base + tid * 4);
  float4 b = *(const float4*)(Bres + base + tid * 4);
  float4 xv;
  xv.x = a.x + b.x; xv.y = a.y + b.y; xv.z = a.z + b.z; xv.w = a.w + b.w;
  float s  = xv.x + xv.y + xv.z + xv.w;
  float s2 = xv.x * xv.x + xv.y * xv.y + xv.z * xv.z + xv.w * xv.w;
#pragma unroll
  for (int d = 1; d < 64; d <<= 1) {
    s  += __shfl_xor(s, d);
    s2 += __shfl_xor(s2, d);
  }
  __shared__ float red[2][4];
  const int wave = tid >> 6;
  if ((tid & 63) == 0) { red[0][wave] = s; red[1][wave] = s2; }
  __syncthreads();
  s  = red[0][0] + red[0][1] + red[0][2] + red[0][3];
  s2 = red[1][0] + red[1][1] + red[1][2] + red[1][3];
  const float mu  = s * (1.0f / 1024.0f);
  const float var = s2 * (1.0f / 1024.0f) - mu * mu;
  const float rs  = rsqrtf(var + 1e-9f);
  float4 gg = *(const float4*)(g + tid * 4);
  float4 bb = *(const float4*)(be + tid * 4);
  float4 y;
  y.x = (xv.x - mu) * rs * gg.x + bb.x;
  y.y = (xv.y - mu) * rs * gg.y + bb.y;
  y.z = (xv.z - mu) * rs * gg.z + bb.z;
  y.w = (xv.w - mu) * rs * gg.w + bb.w;
  *(float4*)(outf + base + tid * 4) = y;
  if (outb) {
    bf16* o = outb + base + tid * 4;
    o[0] = __float2bfloat16(y.x);
    o[1] = __float2bfloat16(y.y);
    o[2] = __float2bfloat16(y.z);
    o[3] = __float2bfloat16(y.w);
  }
}

// ---------------------------------------------------------------------------
extern "C" void kernel_launch(void* const* d_in, const int* in_sizes, int n_in,
                              void* d_out, int out_size, void* d_ws,
                              size_t ws_size, hipStream_t stream) {
  const float* x    = (const float*)d_in[0];
  const float* mask = (const float*)d_in[1];
  const float* wq_w = (const float*)d_in[2];
  const float* wq_b = (const float*)d_in[3];
  const float* wk_w = (const float*)d_in[4];
  const float* wk_b = (const float*)d_in[5];
  const float* wv_w = (const float*)d_in[6];
  const float* wv_b = (const float*)d_in[7];
  const float* wo_w = (const float*)d_in[8];
  const float* wo_b = (const float*)d_in[9];
  const float* f1_w = (const float*)d_in[10];
  const float* f1_b = (const float*)d_in[11];
  const float* f2_w = (const float*)d_in[12];
  const float* f2_b = (const float*)d_in[13];
  const float* ln1_g = (const float*)d_in[14];
  const float* ln1_b = (const float*)d_in[15];
  const float* ln2_g = (const float*)d_in[16];
  const float* ln2_b = (const float*)d_in[17];
  float* out = (float*)d_out;

  char* ws = (char*)d_ws;
  const size_t MB = 1u << 20;
  bf16*  xbf   = (bf16*)(ws + 0 * MB);    // 8 MB
  bf16*  wqT   = (bf16*)(ws + 8 * MB);    // 2 MB each
  bf16*  wkT   = (bf16*)(ws + 10 * MB);
  bf16*  wvT   = (bf16*)(ws + 12 * MB);
  bf16*  woT   = (bf16*)(ws + 14 * MB);
  bf16*  f1T   = (bf16*)(ws + 16 * MB);   // 8 MB
  bf16*  f2T   = (bf16*)(ws + 24 * MB);   // 8 MB
  bf16*  Qb    = (bf16*)(ws + 32 * MB);   // 8 MB
  bf16*  Kb    = (bf16*)(ws + 40 * MB);
  bf16*  Vb    = (bf16*)(ws + 48 * MB);
  bf16*  attnb = (bf16*)(ws + 56 * MB);   // 8 MB
  float* proj  = (float*)(ws + 64 * MB);  // 16 MB
  float* h     = (float*)(ws + 80 * MB);  // 16 MB
  bf16*  hbf   = (bf16*)(ws + 96 * MB);   // 8 MB
  bf16*  ffn1  = (bf16*)(ws + 32 * MB);   // 32 MB, reuses dead Q/K/V/attn
  float* f2o   = proj;                    // reuses dead proj

  // pre-pass: bf16 conversions / weight transposes
  cvt_bf16<<<4096, 256, 0, stream>>>(x, xbf);
  transpose_cvt<<<dim3(32, 32),  256, 0, stream>>>(wq_w, wqT, 1024, 1024);
  transpose_cvt<<<dim3(32, 32),  256, 0, stream>>>(wk_w, wkT, 1024, 1024);
  transpose_cvt<<<dim3(32, 32),  256, 0, stream>>>(wv_w, wvT, 1024, 1024);
  transpose_cvt<<<dim3(32, 32),  256, 0, stream>>>(wo_w, woT, 1024, 1024);
  transpose_cvt<<<dim3(128, 32), 256, 0, stream>>>(f1_w, f1T, 1024, 4096);
  transpose_cvt<<<dim3(32, 128), 256, 0, stream>>>(f2_w, f2T, 4096, 1024);

  const dim3 gE(MTOT / 128, E_DIM / 128);   // (32, 8)
  // Q, K, V projections -> (B*H, S, D) bf16
  gemm_bt<<<gE, 256, 0, stream>>>(xbf, wqT, wq_b, Qb, MTOT, E_DIM, E_DIM, 2);
  gemm_bt<<<gE, 256, 0, stream>>>(xbf, wkT, wk_b, Kb, MTOT, E_DIM, E_DIM, 2);
  gemm_bt<<<gE, 256, 0, stream>>>(xbf, wvT, wv_b, Vb, MTOT, E_DIM, E_DIM, 2);

  // attention
  flash_attn<<<dim3(S_LEN / 64, NB * NH), 256, 0, stream>>>(Qb, Kb, Vb, mask, attnb);

  // output projection (fp32)
  gemm_bt<<<gE, 256, 0, stream>>>(attnb, woT, wo_b, proj, MTOT, E_DIM, E_DIM, 0);

  // h = LN(proj + x), also bf16 copy
  ln_fused<<<MTOT, 256, 0, stream>>>(proj, x, ln1_g, ln1_b, h, hbf);

  // FFN
  gemm_bt<<<dim3(MTOT / 128, FFN / 128), 256, 0, stream>>>(
      hbf, f1T, f1_b, ffn1, MTOT, FFN, E_DIM, 1);
  gemm_bt<<<gE, 256, 0, stream>>>(ffn1, f2T, f2_b, f2o, MTOT, E_DIM, FFN, 0);

  // out = LN(f2o + h)
  ln_fused<<<MTOT, 256, 0, stream>>>(f2o, h, ln2_g, ln2_b, out, nullptr);
}

// Round 2
// 436.188 us; speedup vs baseline: 1.4317x; 1.4317x over previous
//
#include <hip/hip_runtime.h>
#include <hip/hip_bf16.h>
#include <stdint.h>

typedef __hip_bfloat16 bf16;
typedef __attribute__((ext_vector_type(8))) short short8;
typedef __attribute__((ext_vector_type(4))) short short4v;
typedef __attribute__((ext_vector_type(4))) float floatx4;

#define E_DIM 1024
#define S_LEN 2048
#define NB    2
#define NH    16
#define HD    64
#define FFN   4096
#define MTOT  4096   // NB * S_LEN

// ---- async global->LDS, 16B per lane (wave-uniform LDS base + lane*16) ----
__device__ __forceinline__ void gl_lds16(const void* g, void* l) {
  __builtin_amdgcn_global_load_lds(
      (__attribute__((address_space(1))) void*)(g),
      (__attribute__((address_space(3))) void*)(l), 16, 0, 0);
}

// LDS chunk swizzles (chunk = 16B = 8 bf16; 8 chunks per 64-elem row)
__device__ __forceinline__ int fswz_v(int row) { return row & 7; }
__device__ __forceinline__ int fswz_k(int row) {
  return ((row ^ (row >> 3)) & 3) | ((((row >> 3) ^ (row >> 4)) & 1) << 2);
}

// ---------------------------------------------------------------------------
// fp32 -> bf16 convert (4 elems/thread)
// ---------------------------------------------------------------------------
__global__ __launch_bounds__(256)
void cvt_bf16(const float* __restrict__ in, bf16* __restrict__ out) {
  const size_t i = ((size_t)blockIdx.x * 256 + threadIdx.x) * 4;
  float4 v = *(const float4*)(in + i);
  out[i + 0] = __float2bfloat16(v.x);
  out[i + 1] = __float2bfloat16(v.y);
  out[i + 2] = __float2bfloat16(v.z);
  out[i + 3] = __float2bfloat16(v.w);
}

// ---------------------------------------------------------------------------
// batched 1024x1024 transpose+convert: z selects one of 4 (src,dst) pairs
// ---------------------------------------------------------------------------
__global__ __launch_bounds__(256)
void transpose4(const float* __restrict__ s0, const float* __restrict__ s1,
                const float* __restrict__ s2, const float* __restrict__ s3,
                bf16* __restrict__ d0, bf16* __restrict__ d1,
                bf16* __restrict__ d2, bf16* __restrict__ d3) {
  const int z = blockIdx.z;
  const float* in = (z == 0) ? s0 : (z == 1) ? s1 : (z == 2) ? s2 : s3;
  bf16* out = (z == 0) ? d0 : (z == 1) ? d1 : (z == 2) ? d2 : d3;
  __shared__ float tile[32][33];
  const int tx = threadIdx.x & 31;
  const int ty = threadIdx.x >> 5;
  const int c0 = blockIdx.x * 32;
  const int r0 = blockIdx.y * 32;
#pragma unroll
  for (int j = 0; j < 32; j += 8)
    tile[ty + j][tx] = in[(size_t)(r0 + ty + j) * 1024 + c0 + tx];
  __syncthreads();
#pragma unroll
  for (int j = 0; j < 32; j += 8)
    out[(size_t)(c0 + ty + j) * 1024 + r0 + tx] = __float2bfloat16(tile[tx][ty + j]);
}

// generic transpose+convert: in (R,C) fp32 -> out (C,R) bf16
__global__ __launch_bounds__(256)
void transpose_cvt(const float* __restrict__ in, bf16* __restrict__ out,
                   int R, int C) {
  __shared__ float tile[32][33];
  const int tx = threadIdx.x & 31;
  const int ty = threadIdx.x >> 5;
  const int c0 = blockIdx.x * 32;
  const int r0 = blockIdx.y * 32;
#pragma unroll
  for (int j = 0; j < 32; j += 8)
    tile[ty + j][tx] = in[(size_t)(r0 + ty + j) * C + c0 + tx];
  __syncthreads();
#pragma unroll
  for (int j = 0; j < 32; j += 8)
    out[(size_t)(c0 + ty + j) * R + r0 + tx] = __float2bfloat16(tile[tx][ty + j]);
}

// concat biases (Q bias pre-scaled by 0.125)
__global__ __launch_bounds__(256)
void prep_bias(const float* __restrict__ qb, const float* __restrict__ kb,
               const float* __restrict__ vb, float* __restrict__ out) {
  const int i = blockIdx.x * 256 + threadIdx.x;
  float v = (i < 1024) ? qb[i] * 0.125f
                       : ((i < 2048) ? kb[i - 1024] : vb[i - 2048]);
  out[i] = v;
}

// ---------------------------------------------------------------------------
// GEMM: C(M,N) = A(M,K) @ B^T, B stored (N,K) row-major, both bf16.
// 128x128 tile, BK=32, 4 waves x (64x64), 16x16x32 bf16 MFMA (m97 structure).
// mode 0: fp32 row-major store (+bias)
// mode 1: ReLU + bf16 row-major store (+bias)
// mode 2: fused-QKV scatter. N=3072; col>>10 selects Q/K/V.
//         Q scaled 0.125 (bias pre-scaled), Q/K -> (B*H,S,D), V -> (B*H,D,S).
//         Cout = Qb base; Kb = +4M elems; Vt = +8M elems.
// ---------------------------------------------------------------------------
__global__ __launch_bounds__(256)
void gemm_bt(const bf16* __restrict__ A, const bf16* __restrict__ B,
             const float* __restrict__ bias, void* __restrict__ Cout,
             int M, int N, int K, int mode) {
  __shared__ alignas(16) bf16 sA[128 * 32];
  __shared__ alignas(16) bf16 sB[128 * 32];
  const int tid   = threadIdx.x;
  const int wave  = tid >> 6;
  const int lane  = tid & 63;
  const int row16 = lane & 15;
  const int quad  = lane >> 4;
  const int m0 = blockIdx.x * 128;
  const int n0 = blockIdx.y * 128;
  const int wm = (wave >> 1) * 64;
  const int wn = (wave & 1) * 64;

  floatx4 acc[4][4];
#pragma unroll
  for (int i = 0; i < 4; i++)
#pragma unroll
    for (int j = 0; j < 4; j++) {
      floatx4 z = {0.f, 0.f, 0.f, 0.f};
      acc[i][j] = z;
    }

  for (int k0 = 0; k0 < K; k0 += 32) {
#pragma unroll
    for (int j = 0; j < 2; ++j) {
      const int chunk = wave * 2 + j;
      const int e = chunk * 512 + lane * 8;
      const int r = e >> 5;
      const int kk = e & 31;
      gl_lds16(A + (size_t)(m0 + r) * K + k0 + kk, sA + chunk * 512);
      gl_lds16(B + (size_t)(n0 + r) * K + k0 + kk, sB + chunk * 512);
    }
    __syncthreads();

    short8 af[4], bfr[4];
#pragma unroll
    for (int i = 0; i < 4; i++) {
      af[i]  = *(const short8*)(sA + (wm + i * 16 + row16) * 32 + quad * 8);
      bfr[i] = *(const short8*)(sB + (wn + i * 16 + row16) * 32 + quad * 8);
    }
#pragma unroll
    for (int mi = 0; mi < 4; mi++)
#pragma unroll
      for (int ni = 0; ni < 4; ni++)
        acc[mi][ni] = __builtin_amdgcn_mfma_f32_16x16x32_bf16(
            af[mi], bfr[ni], acc[mi][ni], 0, 0, 0);
    __syncthreads();
  }

  float bval[4];
#pragma unroll
  for (int ni = 0; ni < 4; ni++) bval[ni] = bias[n0 + wn + ni * 16 + row16];

#pragma unroll
  for (int mi = 0; mi < 4; mi++) {
#pragma unroll
    for (int ni = 0; ni < 4; ni++) {
      const int col = n0 + wn + ni * 16 + row16;
      if (mode == 0) {
#pragma unroll
        for (int r = 0; r < 4; r++) {
          const int row = m0 + wm + mi * 16 + quad * 4 + r;
          ((float*)Cout)[(size_t)row * N + col] = acc[mi][ni][r] + bval[ni];
        }
      } else if (mode == 1) {
#pragma unroll
        for (int r = 0; r < 4; r++) {
          const int row = m0 + wm + mi * 16 + quad * 4 + r;
          float v = acc[mi][ni][r] + bval[ni];
          v = v > 0.f ? v : 0.f;
          ((bf16*)Cout)[(size_t)row * N + col] = __float2bfloat16(v);
        }
      } else {
        // fused QKV scatter
        const int mat = col >> 10;
        const int c10 = col & 1023;
        const int hh = c10 >> 6, dd = c10 & 63;
        const float scl = (mat == 0) ? 0.125f : 1.0f;
        bf16* qout = (bf16*)Cout;
        const int rbase = m0 + wm + mi * 16 + quad * 4;
        const int b = rbase >> 11, s = rbase & 2047;
        const size_t bh = (size_t)b * NH + hh;
        if (mat == 2) {
          bf16* vt = qout + (1 << 23);
          short4v pv;
#pragma unroll
          for (int r = 0; r < 4; r++) {
            bf16 t = __float2bfloat16(acc[mi][ni][r] + bval[ni]);
            pv[r] = *(short*)&t;
          }
          *(short4v*)(vt + (bh * HD + dd) * S_LEN + s) = pv;
        } else {
          bf16* o = (mat == 1) ? (qout + (1 << 22)) : qout;
#pragma unroll
          for (int r = 0; r < 4; r++) {
            float v = acc[mi][ni][r] * scl + bval[ni];
            o[(bh * S_LEN + s + r) * HD + dd] = __float2bfloat16(v);
          }
        }
      }
    }
  }
}

// ---------------------------------------------------------------------------
// Flash attention v2: one block per (64-q tile, bh). S^T orientation.
// Q,K: (B*H,S,D) bf16 (Q pre-scaled by 0.125); Vt: (B*H,D,S) bf16.
// Out: (B,S,E) bf16, heads merged.
// Per wave: 16 q rows (n=row16). Key permutation sigma makes QK^T C-layout
// identical to PV B-operand layout -> no P transform at all.
// ---------------------------------------------------------------------------
__global__ __launch_bounds__(256, 4)
void flash_attn(const bf16* __restrict__ Q, const bf16* __restrict__ K,
                const bf16* __restrict__ Vt, const float* __restrict__ mask,
                bf16* __restrict__ Out) {
  __shared__ alignas(16) bf16 sK[64 * 64];   // [key][d], chunk-swizzled fswz_k
  __shared__ alignas(16) bf16 sV[64 * 64];   // [d][key], chunk-swizzled fswz_v
  __shared__ alignas(16) float sM[S_LEN];    // -1e12 * mask[b][*]

  const int tid   = threadIdx.x;
  const int wave  = tid >> 6;
  const int lane  = tid & 63;
  const int row16 = lane & 15;   // q within wave-group / MFMA n-index
  const int quad  = lane >> 4;
  const int bh = blockIdx.y;
  const int b = bh >> 4, h = bh & 15;
  const int q0 = blockIdx.x * 64;
  const int qg = q0 + wave * 16 + row16;   // this lane's q

  // Q fragments (B-operand): Q[qg][d], d = ks*32 + quad*8 + j
  const bf16* qp = Q + ((size_t)bh * S_LEN + qg) * HD;
  short8 qf0 = *(const short8*)(qp + quad * 8);
  short8 qf1 = *(const short8*)(qp + 32 + quad * 8);

  // mask -> LDS, pre-multiplied
  for (int i = tid; i < S_LEN / 4; i += 256) {
    float4 mv = ((const float4*)(mask + (size_t)b * S_LEN))[i];
    float4 w = {-1e12f * mv.x, -1e12f * mv.y, -1e12f * mv.z, -1e12f * mv.w};
    ((float4*)sM)[i] = w;
  }

  float m_i = -1e30f, l_i = 0.f;
  floatx4 ov[4];
#pragma unroll
  for (int i = 0; i < 4; i++) { floatx4 z = {0.f,0.f,0.f,0.f}; ov[i] = z; }

  const bf16* Kbase = K + (size_t)bh * S_LEN * HD;
  const bf16* Vbase = Vt + (size_t)bh * HD * S_LEN;

  for (int kt = 0; kt < S_LEN / 64; ++kt) {
    const bf16* Kg = Kbase + (size_t)kt * 64 * HD;
    const bf16* Vg = Vbase + kt * 64;
    // stage K and Vt tiles (swizzled chunk placement via global address)
#pragma unroll
    for (int j = 0; j < 2; ++j) {
      const int ch = wave * 2 + j;
      const int row = ch * 8 + (lane >> 3);
      const int sc_ = lane & 7;
      gl_lds16(Kg + row * 64 + ((sc_ ^ fswz_k(row)) * 8), sK + ch * 512);
      gl_lds16(Vg + (size_t)row * S_LEN + ((sc_ ^ fswz_v(row)) * 8), sV + ch * 512);
    }
    __syncthreads();

    // S^T tiles: sc[mi][r] = score(q=row16, key = kt*64 + 8*quad + r + 4*(mi&1) + 32*(mi>>1))
    floatx4 sc[4];
#pragma unroll
    for (int mi = 0; mi < 4; mi++) {
      const int row = ((row16 >> 2) << 3) + (row16 & 3) + ((mi & 1) << 2) + ((mi >> 1) << 5);
      const int fk = fswz_k(row);
      short8 kf0 = *(const short8*)(sK + row * 64 + ((quad ^ fk) << 3));
      short8 kf1 = *(const short8*)(sK + row * 64 + (((4 + quad) ^ fk) << 3));
      floatx4 z = {0.f, 0.f, 0.f, 0.f};
      z = __builtin_amdgcn_mfma_f32_16x16x32_bf16(kf0, qf0, z, 0, 0, 0);
      sc[mi] = __builtin_amdgcn_mfma_f32_16x16x32_bf16(kf1, qf1, z, 0, 0, 0);
    }

    // mask add (broadcast float4 per mi)
#pragma unroll
    for (int mi = 0; mi < 4; mi++) {
      float4 mv = *(const float4*)(sM + kt * 64 + (quad << 3) + ((mi & 1) << 2) + ((mi >> 1) << 5));
      sc[mi][0] += mv.x; sc[mi][1] += mv.y; sc[mi][2] += mv.z; sc[mi][3] += mv.w;
    }

    // online softmax: reduce 16 in-lane + across 4 quads
    float t = sc[0][0];
#pragma unroll
    for (int mi = 0; mi < 4; mi++)
#pragma unroll
      for (int r = 0; r < 4; r++) t = fmaxf(t, sc[mi][r]);
    t = fmaxf(t, __shfl_xor(t, 16));
    t = fmaxf(t, __shfl_xor(t, 32));
    const float m_new = fmaxf(m_i, t);
    const float alpha = __expf(m_i - m_new);
    m_i = m_new;
    float tsum = 0.f;
#pragma unroll
    for (int mi = 0; mi < 4; mi++)
#pragma unroll
      for (int r = 0; r < 4; r++) {
        float p = __expf(sc[mi][r] - m_new);
        sc[mi][r] = p;
        tsum += p;
      }
    tsum += __shfl_xor(tsum, 16);
    tsum += __shfl_xor(tsum, 32);
    l_i = l_i * alpha + tsum;

    // pack P into PV B-operand fragments (pure in-lane!)
    short8 pf[2];
#pragma unroll
    for (int ks = 0; ks < 2; ks++)
#pragma unroll
      for (int jp = 0; jp < 4; jp++) {
        const int mi = 2 * ks + (jp >> 1);
        const int r0 = (jp & 1) * 2;
        bf16 p0 = __float2bfloat16(sc[mi][r0]);
        bf16 p1 = __float2bfloat16(sc[mi][r0 + 1]);
        pf[ks][2 * jp]     = *(short*)&p0;
        pf[ks][2 * jp + 1] = *(short*)&p1;
      }

    // rescale O, then O^T += V^T . P
#pragma unroll
    for (int mi = 0; mi < 4; mi++)
#pragma unroll
      for (int r = 0; r < 4; r++) ov[mi][r] *= alpha;
#pragma unroll
    for (int mi = 0; mi < 4; mi++) {
      const int row = mi * 16 + row16;   // d
      const int fv = fswz_v(row);
      short8 v0 = *(const short8*)(sV + row * 64 + ((quad ^ fv) << 3));
      short8 v1 = *(const short8*)(sV + row * 64 + (((4 + quad) ^ fv) << 3));
      ov[mi] = __builtin_amdgcn_mfma_f32_16x16x32_bf16(v0, pf[0], ov[mi], 0, 0, 0);
      ov[mi] = __builtin_amdgcn_mfma_f32_16x16x32_bf16(v1, pf[1], ov[mi], 0, 0, 0);
    }
    __syncthreads();
  }

  // epilogue: O^T[d][q] / l ; d = mi*16 + quad*4 + r, q = row16
  const float inv = 1.0f / l_i;
#pragma unroll
  for (int mi = 0; mi < 4; mi++) {
    short4v pv;
#pragma unroll
    for (int r = 0; r < 4; r++) {
      bf16 t = __float2bfloat16(ov[mi][r] * inv);
      pv[r] = *(short*)&t;
    }
    *(short4v*)(Out + ((size_t)(b * S_LEN + qg)) * E_DIM + h * HD + mi * 16 + quad * 4) = pv;
  }
}

// ---------------------------------------------------------------------------
// Fused residual + LayerNorm (1024 cols, 4/thread, one block per row)
// ---------------------------------------------------------------------------
__global__ __launch_bounds__(256)
void ln_fused(const float* __restrict__ A, const float* __restrict__ Bres,
              const float* __restrict__ g, const float* __restrict__ be,
              float* __restrict__ outf, bf16* __restrict__ outb) {
  const int row = blockIdx.x;
  const int tid = threadIdx.x;
  const size_t base = (size_t)row * 1024;
  float4 a = *(const float4*)(A + base + tid * 4);
  float4 b = *(const float4*)(Bres + base + tid * 4);
  float4 xv;
  xv.x = a.x + b.x; xv.y = a.y + b.y; xv.z = a.z + b.z; xv.w = a.w + b.w;
  float s  = xv.x + xv.y + xv.z + xv.w;
  float s2 = xv.x * xv.x + xv.y * xv.y + xv.z * xv.z + xv.w * xv.w;
#pragma unroll
  for (int d = 1; d < 64; d <<= 1) {
    s  += __shfl_xor(s, d);
    s2 += __shfl_xor(s2, d);
  }
  __shared__ float red[2][4];
  const int wave = tid >> 6;
  if ((tid & 63) == 0) { red[0][wave] = s; red[1][wave] = s2; }
  __syncthreads();
  s  = red[0][0] + red[0][1] + red[0][2] + red[0][3];
  s2 = red[1][0] + red[1][1] + red[1][2] + red[1][3];
  const float mu  = s * (1.0f / 1024.0f);
  const float var = s2 * (1.0f / 1024.0f) - mu * mu;
  const float rs  = rsqrtf(var + 1e-9f);
  float4 gg = *(const float4*)(g + tid * 4);
  float4 bb = *(const float4*)(be + tid * 4);
  float4 y;
  y.x = (xv.x - mu) * rs * gg.x + bb.x;
  y.y = (xv.y - mu) * rs * gg.y + bb.y;
  y.z = (xv.z - mu) * rs * gg.z + bb.z;
  y.w = (xv.w - mu) * rs * gg.w + bb.w;
  *(float4*)(outf + base + tid * 4) = y;
  if (outb) {
    bf16* o = outb + base + tid * 4;
    o[0] = __float2bfloat16(y.x);
    o[1] = __float2bfloat16(y.y);
    o[2] = __float2bfloat16(y.z);
    o[3] = __float2bfloat16(y.w);
  }
}

// ---------------------------------------------------------------------------
extern "C" void kernel_launch(void* const* d_in, const int* in_sizes, int n_in,
                              void* d_out, int out_size, void* d_ws,
                              size_t ws_size, hipStream_t stream) {
  const float* x    = (const float*)d_in[0];
  const float* mask = (const float*)d_in[1];
  const float* wq_w = (const float*)d_in[2];
  const float* wq_b = (const float*)d_in[3];
  const float* wk_w = (const float*)d_in[4];
  const float* wk_b = (const float*)d_in[5];
  const float* wv_w = (const float*)d_in[6];
  const float* wv_b = (const float*)d_in[7];
  const float* wo_w = (const float*)d_in[8];
  const float* wo_b = (const float*)d_in[9];
  const float* f1_w = (const float*)d_in[10];
  const float* f1_b = (const float*)d_in[11];
  const float* f2_w = (const float*)d_in[12];
  const float* f2_b = (const float*)d_in[13];
  const float* ln1_g = (const float*)d_in[14];
  const float* ln1_b = (const float*)d_in[15];
  const float* ln2_g = (const float*)d_in[16];
  const float* ln2_b = (const float*)d_in[17];
  float* out = (float*)d_out;

  char* ws = (char*)d_ws;
  const size_t MB = 1u << 20;
  bf16*  xbf   = (bf16*)(ws + 0 * MB);    // 8 MB   (dead after QKV gemm)
  bf16*  W3T   = (bf16*)(ws + 8 * MB);    // 6 MB   (dead after QKV gemm)
  bf16*  woT   = (bf16*)(ws + 14 * MB);   // 2 MB   (dead after Wo gemm)
  bf16*  f1T   = (bf16*)(ws + 16 * MB);   // 8 MB
  bf16*  f2T   = (bf16*)(ws + 24 * MB);   // 8 MB
  float* bqkv  = (float*)(ws + 32 * MB);  // 12 KB  (1 MB reserved)
  bf16*  Qb    = (bf16*)(ws + 33 * MB);   // 8 MB  -- Kb/Vt at +8/+16 MB
  bf16*  attnb = (bf16*)(ws + 0 * MB);    // 8 MB, reuses xbf region
  float* proj  = (float*)(ws + 57 * MB);  // 16 MB
  float* h     = (float*)(ws + 73 * MB);  // 16 MB
  bf16*  hbf   = (bf16*)(ws + 89 * MB);   // 8 MB  (total 97 MB)
  bf16*  ffn1  = (bf16*)(ws + 33 * MB);   // 32 MB, reuses Qb/Kb/Vt (+proj head dead)
  float* f2o   = (float*)(ws + 0 * MB);   // 16 MB, reuses attnb/W3T/woT region

  // pre-pass
  cvt_bf16<<<4096, 256, 0, stream>>>(x, xbf);
  transpose4<<<dim3(32, 32, 4), 256, 0, stream>>>(
      wq_w, wk_w, wv_w, wo_w,
      W3T, W3T + 1024 * 1024, W3T + 2 * 1024 * 1024, woT);
  transpose_cvt<<<dim3(128, 32), 256, 0, stream>>>(f1_w, f1T, 1024, 4096);
  transpose_cvt<<<dim3(32, 128), 256, 0, stream>>>(f2_w, f2T, 4096, 1024);
  prep_bias<<<12, 256, 0, stream>>>(wq_b, wk_b, wv_b, bqkv);

  // fused QKV projection -> Qb (B*H,S,D), Kb (B*H,S,D), Vt (B*H,D,S)
  gemm_bt<<<dim3(32, 24), 256, 0, stream>>>(xbf, W3T, bqkv, Qb,
                                            MTOT, 3 * E_DIM, E_DIM, 2);

  // attention
  flash_attn<<<dim3(S_LEN / 64, NB * NH), 256, 0, stream>>>(
      Qb, Qb + (1 << 22), Qb + (1 << 23), mask, attnb);

  // output projection (fp32)
  gemm_bt<<<dim3(32, 8), 256, 0, stream>>>(attnb, woT, wo_b, proj,
                                           MTOT, E_DIM, E_DIM, 0);

  // h = LN(proj + x)
  ln_fused<<<MTOT, 256, 0, stream>>>(proj, x, ln1_g, ln1_b, h, hbf);

  // FFN
  gemm_bt<<<dim3(32, 32), 256, 0, stream>>>(hbf, f1T, f1_b, ffn1,
                                            MTOT, FFN, E_DIM, 1);
  gemm_bt<<<dim3(32, 8), 256, 0, stream>>>(ffn1, f2T, f2_b, f2o,
                                           MTOT, E_DIM, FFN, 0);

  // out = LN(f2o + h)
  ln_fused<<<MTOT, 256, 0, stream>>>(f2o, h, ln2_g, ln2_b, out, nullptr);
}

// Round 4
// 391.313 us; speedup vs baseline: 1.5959x; 1.1147x over previous
//
#include <hip/hip_runtime.h>
#include <hip/hip_bf16.h>
#include <stdint.h>

typedef __hip_bfloat16 bf16;
typedef __attribute__((ext_vector_type(8))) short short8;
typedef __attribute__((ext_vector_type(4))) short short4v;
typedef __attribute__((ext_vector_type(4))) float floatx4;

#define E_DIM 1024
#define S_LEN 2048
#define NB    2
#define NH    16
#define HD    64
#define FFN   4096
#define MTOT  4096   // NB * S_LEN

// ---- async global->LDS, 16B per lane (wave-uniform LDS base + lane*16) ----
__device__ __forceinline__ void gl_lds16(const void* g, void* l) {
  __builtin_amdgcn_global_load_lds(
      (__attribute__((address_space(1))) void*)(g),
      (__attribute__((address_space(3))) void*)(l), 16, 0, 0);
}

// LDS chunk swizzles (chunk = 16B = 8 bf16; 8 chunks per 64-elem row)
__device__ __forceinline__ int fswz_v(int row) { return row & 7; }
__device__ __forceinline__ int fswz_k(int row) {
  return ((row ^ (row >> 3)) & 3) | ((((row >> 3) ^ (row >> 4)) & 1) << 2);
}

__device__ __forceinline__ float bf16bits2float(short s) {
  union { unsigned u; float f; } c;
  c.u = ((unsigned)(unsigned short)s) << 16;
  return c.f;
}

// ---------------------------------------------------------------------------
// fp32 -> bf16 convert (4 elems/thread)
// ---------------------------------------------------------------------------
__global__ __launch_bounds__(256)
void cvt_bf16(const float* __restrict__ in, bf16* __restrict__ out) {
  const size_t i = ((size_t)blockIdx.x * 256 + threadIdx.x) * 4;
  float4 v = *(const float4*)(in + i);
  out[i + 0] = __float2bfloat16(v.x);
  out[i + 1] = __float2bfloat16(v.y);
  out[i + 2] = __float2bfloat16(v.z);
  out[i + 3] = __float2bfloat16(v.w);
}

// ---------------------------------------------------------------------------
// All weight transposes in one kernel: 12 z-slices of 1024x1024 blocks.
// z 0..2: wq/wk/wv -> W3T rows [z*1024..), z 3: wo -> woT,
// z 4..7: f1 cols (z-4)*1024.. -> f1T rows,  z 8..11: f2 rows -> f2T cols.
// ---------------------------------------------------------------------------
__global__ __launch_bounds__(256)
void transpose_all(const float* __restrict__ wq, const float* __restrict__ wk,
                   const float* __restrict__ wv, const float* __restrict__ wo,
                   const float* __restrict__ f1, const float* __restrict__ f2,
                   bf16* __restrict__ W3T, bf16* __restrict__ woT,
                   bf16* __restrict__ f1T, bf16* __restrict__ f2T) {
  const int z = blockIdx.z;
  const float* in;
  bf16* out;
  int inStride, outStride, rOff, cOff;
  if (z < 4) {
    in = (z == 0) ? wq : (z == 1) ? wk : (z == 2) ? wv : wo;
    out = (z < 3) ? (W3T + (size_t)z * 1024 * 1024) : woT;
    inStride = 1024; outStride = 1024; rOff = 0; cOff = 0;
  } else if (z < 8) {
    in = f1; out = f1T; inStride = 4096; outStride = 1024;
    rOff = 0; cOff = (z - 4) * 1024;
  } else {
    in = f2; out = f2T; inStride = 1024; outStride = 4096;
    rOff = (z - 8) * 1024; cOff = 0;
  }
  __shared__ float tile[32][33];
  const int tx = threadIdx.x & 31;
  const int ty = threadIdx.x >> 5;
  const int c0 = blockIdx.x * 32;
  const int r0 = blockIdx.y * 32;
#pragma unroll
  for (int j = 0; j < 32; j += 8)
    tile[ty + j][tx] =
        in[(size_t)(rOff + r0 + ty + j) * inStride + cOff + c0 + tx];
  __syncthreads();
#pragma unroll
  for (int j = 0; j < 32; j += 8)
    out[(size_t)(cOff + c0 + ty + j) * outStride + rOff + r0 + tx] =
        __float2bfloat16(tile[tx][ty + j]);
}

// concat biases (Q bias pre-scaled by 0.125)
__global__ __launch_bounds__(256)
void prep_bias(const float* __restrict__ qb, const float* __restrict__ kb,
               const float* __restrict__ vb, float* __restrict__ out) {
  const int i = blockIdx.x * 256 + threadIdx.x;
  float v = (i < 1024) ? qb[i] * 0.125f
                       : ((i < 2048) ? kb[i - 1024] : vb[i - 2048]);
  out[i] = v;
}

// ---------------------------------------------------------------------------
// GEMM: C(M,N) = A(M,K) @ B^T, B stored (N,K) row-major, both bf16.
// 128x128 tile, BK=32, 4 waves x (64x64), 16x16x32 bf16 MFMA (m97 structure).
// Split-K via gridDim.z: block z handles K range [z*Kpart, (z+1)*Kpart);
// lda = full row stride of A and B.
// mode 0: fp32 store, NO bias, output offset z*M*N (split-K partial)
// mode 1: ReLU + bf16 row-major store (+bias)
// mode 2: fused-QKV scatter. N=3072; col>>10 selects Q/K/V.
//         Q scaled 0.125 (bias pre-scaled), Q/K -> (B*H,S,D), V -> (B*H,D,S).
// ---------------------------------------------------------------------------
__global__ __launch_bounds__(256)
void gemm_bt(const bf16* __restrict__ A, const bf16* __restrict__ B,
             const float* __restrict__ bias, void* __restrict__ Cout,
             int M, int N, int Kpart, int lda, int mode) {
  __shared__ alignas(16) bf16 sA[128 * 32];
  __shared__ alignas(16) bf16 sB[128 * 32];
  const int tid   = threadIdx.x;
  const int wave  = tid >> 6;
  const int lane  = tid & 63;
  const int row16 = lane & 15;
  const int quad  = lane >> 4;
  const int m0 = blockIdx.x * 128;
  const int n0 = blockIdx.y * 128;
  const int wm = (wave >> 1) * 64;
  const int wn = (wave & 1) * 64;
  const int koff = blockIdx.z * Kpart;

  floatx4 acc[4][4];
#pragma unroll
  for (int i = 0; i < 4; i++)
#pragma unroll
    for (int j = 0; j < 4; j++) {
      floatx4 z = {0.f, 0.f, 0.f, 0.f};
      acc[i][j] = z;
    }

  for (int k0 = koff; k0 < koff + Kpart; k0 += 32) {
#pragma unroll
    for (int j = 0; j < 2; ++j) {
      const int chunk = wave * 2 + j;
      const int e = chunk * 512 + lane * 8;
      const int r = e >> 5;
      const int kk = e & 31;
      gl_lds16(A + (size_t)(m0 + r) * lda + k0 + kk, sA + chunk * 512);
      gl_lds16(B + (size_t)(n0 + r) * lda + k0 + kk, sB + chunk * 512);
    }
    __syncthreads();

    short8 af[4], bfr[4];
#pragma unroll
    for (int i = 0; i < 4; i++) {
      af[i]  = *(const short8*)(sA + (wm + i * 16 + row16) * 32 + quad * 8);
      bfr[i] = *(const short8*)(sB + (wn + i * 16 + row16) * 32 + quad * 8);
    }
#pragma unroll
    for (int mi = 0; mi < 4; mi++)
#pragma unroll
      for (int ni = 0; ni < 4; ni++)
        acc[mi][ni] = __builtin_amdgcn_mfma_f32_16x16x32_bf16(
            af[mi], bfr[ni], acc[mi][ni], 0, 0, 0);
    __syncthreads();
  }

  float bval[4] = {0.f, 0.f, 0.f, 0.f};
  if (mode != 0) {
#pragma unroll
    for (int ni = 0; ni < 4; ni++) bval[ni] = bias[n0 + wn + ni * 16 + row16];
  }

#pragma unroll
  for (int mi = 0; mi < 4; mi++) {
#pragma unroll
    for (int ni = 0; ni < 4; ni++) {
      const int col = n0 + wn + ni * 16 + row16;
      if (mode == 0) {
        float* co = (float*)Cout + (size_t)blockIdx.z * M * N;
#pragma unroll
        for (int r = 0; r < 4; r++) {
          const int row = m0 + wm + mi * 16 + quad * 4 + r;
          co[(size_t)row * N + col] = acc[mi][ni][r];
        }
      } else if (mode == 1) {
#pragma unroll
        for (int r = 0; r < 4; r++) {
          const int row = m0 + wm + mi * 16 + quad * 4 + r;
          float v = acc[mi][ni][r] + bval[ni];
          v = v > 0.f ? v : 0.f;
          ((bf16*)Cout)[(size_t)row * N + col] = __float2bfloat16(v);
        }
      } else {
        // fused QKV scatter
        const int mat = col >> 10;
        const int c10 = col & 1023;
        const int hh = c10 >> 6, dd = c10 & 63;
        const float scl = (mat == 0) ? 0.125f : 1.0f;
        bf16* qout = (bf16*)Cout;
        const int rbase = m0 + wm + mi * 16 + quad * 4;
        const int b = rbase >> 11, s = rbase & 2047;
        const size_t bh = (size_t)b * NH + hh;
        if (mat == 2) {
          bf16* vt = qout + (1 << 23);
          short4v pv;
#pragma unroll
          for (int r = 0; r < 4; r++) {
            bf16 t = __float2bfloat16(acc[mi][ni][r] + bval[ni]);
            pv[r] = *(short*)&t;
          }
          *(short4v*)(vt + (bh * HD + dd) * S_LEN + s) = pv;
        } else {
          bf16* o = (mat == 1) ? (qout + (1 << 22)) : qout;
#pragma unroll
          for (int r = 0; r < 4; r++) {
            float v = acc[mi][ni][r] * scl + bval[ni];
            o[(bh * S_LEN + s + r) * HD + dd] = __float2bfloat16(v);
          }
        }
      }
    }
  }
}

// ---------------------------------------------------------------------------
// Flash attention: one block per (64-q tile, bh). S^T orientation.
// Q,K: (B*H,S,D) bf16 (Q pre-scaled by 0.125); Vt: (B*H,D,S) bf16.
// Out: (B,S,E) bf16, heads merged. Key permutation sigma makes QK^T C-layout
// identical to PV B-operand layout -> no P transform at all.
// ---------------------------------------------------------------------------
__global__ __launch_bounds__(256, 4)
void flash_attn(const bf16* __restrict__ Q, const bf16* __restrict__ K,
                const bf16* __restrict__ Vt, const float* __restrict__ mask,
                bf16* __restrict__ Out) {
  __shared__ alignas(16) bf16 sK[64 * 64];   // [key][d], chunk-swizzled fswz_k
  __shared__ alignas(16) bf16 sV[64 * 64];   // [d][key], chunk-swizzled fswz_v
  __shared__ alignas(16) float sM[S_LEN];    // -1e12 * mask[b][*]

  const int tid   = threadIdx.x;
  const int wave  = tid >> 6;
  const int lane  = tid & 63;
  const int row16 = lane & 15;
  const int quad  = lane >> 4;
  const int bh = blockIdx.y;
  const int b = bh >> 4, h = bh & 15;
  const int q0 = blockIdx.x * 64;
  const int qg = q0 + wave * 16 + row16;

  const bf16* qp = Q + ((size_t)bh * S_LEN + qg) * HD;
  short8 qf0 = *(const short8*)(qp + quad * 8);
  short8 qf1 = *(const short8*)(qp + 32 + quad * 8);

  for (int i = tid; i < S_LEN / 4; i += 256) {
    float4 mv = ((const float4*)(mask + (size_t)b * S_LEN))[i];
    float4 w = {-1e12f * mv.x, -1e12f * mv.y, -1e12f * mv.z, -1e12f * mv.w};
    ((float4*)sM)[i] = w;
  }

  float m_i = -1e30f, l_i = 0.f;
  floatx4 ov[4];
#pragma unroll
  for (int i = 0; i < 4; i++) { floatx4 z = {0.f,0.f,0.f,0.f}; ov[i] = z; }

  const bf16* Kbase = K + (size_t)bh * S_LEN * HD;
  const bf16* Vbase = Vt + (size_t)bh * HD * S_LEN;

  for (int kt = 0; kt < S_LEN / 64; ++kt) {
    const bf16* Kg = Kbase + (size_t)kt * 64 * HD;
    const bf16* Vg = Vbase + kt * 64;
#pragma unroll
    for (int j = 0; j < 2; ++j) {
      const int ch = wave * 2 + j;
      const int row = ch * 8 + (lane >> 3);
      const int sc_ = lane & 7;
      gl_lds16(Kg + row * 64 + ((sc_ ^ fswz_k(row)) * 8), sK + ch * 512);
      gl_lds16(Vg + (size_t)row * S_LEN + ((sc_ ^ fswz_v(row)) * 8), sV + ch * 512);
    }
    __syncthreads();

    floatx4 sc[4];
#pragma unroll
    for (int mi = 0; mi < 4; mi++) {
      const int row = ((row16 >> 2) << 3) + (row16 & 3) + ((mi & 1) << 2) + ((mi >> 1) << 5);
      const int fk = fswz_k(row);
      short8 kf0 = *(const short8*)(sK + row * 64 + ((quad ^ fk) << 3));
      short8 kf1 = *(const short8*)(sK + row * 64 + (((4 + quad) ^ fk) << 3));
      floatx4 z = {0.f, 0.f, 0.f, 0.f};
      z = __builtin_amdgcn_mfma_f32_16x16x32_bf16(kf0, qf0, z, 0, 0, 0);
      sc[mi] = __builtin_amdgcn_mfma_f32_16x16x32_bf16(kf1, qf1, z, 0, 0, 0);
    }

#pragma unroll
    for (int mi = 0; mi < 4; mi++) {
      float4 mv = *(const float4*)(sM + kt * 64 + (quad << 3) + ((mi & 1) << 2) + ((mi >> 1) << 5));
      sc[mi][0] += mv.x; sc[mi][1] += mv.y; sc[mi][2] += mv.z; sc[mi][3] += mv.w;
    }

    float t = sc[0][0];
#pragma unroll
    for (int mi = 0; mi < 4; mi++)
#pragma unroll
      for (int r = 0; r < 4; r++) t = fmaxf(t, sc[mi][r]);
    t = fmaxf(t, __shfl_xor(t, 16));
    t = fmaxf(t, __shfl_xor(t, 32));
    const float m_new = fmaxf(m_i, t);
    const float alpha = __expf(m_i - m_new);
    m_i = m_new;
    float tsum = 0.f;
#pragma unroll
    for (int mi = 0; mi < 4; mi++)
#pragma unroll
      for (int r = 0; r < 4; r++) {
        float p = __expf(sc[mi][r] - m_new);
        sc[mi][r] = p;
        tsum += p;
      }
    tsum += __shfl_xor(tsum, 16);
    tsum += __shfl_xor(tsum, 32);
    l_i = l_i * alpha + tsum;

    short8 pf[2];
#pragma unroll
    for (int ks = 0; ks < 2; ks++)
#pragma unroll
      for (int jp = 0; jp < 4; jp++) {
        const int mi = 2 * ks + (jp >> 1);
        const int r0 = (jp & 1) * 2;
        bf16 p0 = __float2bfloat16(sc[mi][r0]);
        bf16 p1 = __float2bfloat16(sc[mi][r0 + 1]);
        pf[ks][2 * jp]     = *(short*)&p0;
        pf[ks][2 * jp + 1] = *(short*)&p1;
      }

#pragma unroll
    for (int mi = 0; mi < 4; mi++)
#pragma unroll
      for (int r = 0; r < 4; r++) ov[mi][r] *= alpha;
#pragma unroll
    for (int mi = 0; mi < 4; mi++) {
      const int row = mi * 16 + row16;
      const int fv = fswz_v(row);
      short8 v0 = *(const short8*)(sV + row * 64 + ((quad ^ fv) << 3));
      short8 v1 = *(const short8*)(sV + row * 64 + (((4 + quad) ^ fv) << 3));
      ov[mi] = __builtin_amdgcn_mfma_f32_16x16x32_bf16(v0, pf[0], ov[mi], 0, 0, 0);
      ov[mi] = __builtin_amdgcn_mfma_f32_16x16x32_bf16(v1, pf[1], ov[mi], 0, 0, 0);
    }
    __syncthreads();
  }

  const float inv = 1.0f / l_i;
#pragma unroll
  for (int mi = 0; mi < 4; mi++) {
    short4v pv;
#pragma unroll
    for (int r = 0; r < 4; r++) {
      bf16 t = __float2bfloat16(ov[mi][r] * inv);
      pv[r] = *(short*)&t;
    }
    *(short4v*)(Out + ((size_t)(b * S_LEN + qg)) * E_DIM + h * HD + mi * 16 + quad * 4) = pv;
  }
}

// ---------------------------------------------------------------------------
// Split-K reduce + residual + bias + LayerNorm, one block per row.
// xv = p0 + p1 + bias + (resf ? resf : fp32(resb)); LN(xv)*g + be.
// Stores outf (fp32) and/or outb (bf16) if non-null.
// ---------------------------------------------------------------------------
__global__ __launch_bounds__(256)
void ln_reduce(const float* __restrict__ p0, const float* __restrict__ p1,
               const float* __restrict__ resf, const bf16* __restrict__ resb,
               const float* __restrict__ bias, const float* __restrict__ g,
               const float* __restrict__ be, float* __restrict__ outf,
               bf16* __restrict__ outb) {
  const int row = blockIdx.x;
  const int tid = threadIdx.x;
  const size_t base = (size_t)row * 1024;
  const int c = tid * 4;
  float4 a = *(const float4*)(p0 + base + c);
  float4 bq = *(const float4*)(p1 + base + c);
  float4 rv;
  if (resf) {
    rv = *(const float4*)(resf + base + c);
  } else {
    short4v rb = *(const short4v*)((const short*)resb + base + c);
    rv.x = bf16bits2float(rb[0]);
    rv.y = bf16bits2float(rb[1]);
    rv.z = bf16bits2float(rb[2]);
    rv.w = bf16bits2float(rb[3]);
  }
  float4 bi = *(const float4*)(bias + c);
  float4 xv;
  xv.x = a.x + bq.x + rv.x + bi.x;
  xv.y = a.y + bq.y + rv.y + bi.y;
  xv.z = a.z + bq.z + rv.z + bi.z;
  xv.w = a.w + bq.w + rv.w + bi.w;
  float s  = xv.x + xv.y + xv.z + xv.w;
  float s2 = xv.x * xv.x + xv.y * xv.y + xv.z * xv.z + xv.w * xv.w;
#pragma unroll
  for (int d = 1; d < 64; d <<= 1) {
    s  += __shfl_xor(s, d);
    s2 += __shfl_xor(s2, d);
  }
  __shared__ float red[2][4];
  const int wave = tid >> 6;
  if ((tid & 63) == 0) { red[0][wave] = s; red[1][wave] = s2; }
  __syncthreads();
  s  = red[0][0] + red[0][1] + red[0][2] + red[0][3];
  s2 = red[1][0] + red[1][1] + red[1][2] + red[1][3];
  const float mu  = s * (1.0f / 1024.0f);
  const float var = s2 * (1.0f / 1024.0f) - mu * mu;
  const float rs  = rsqrtf(var + 1e-9f);
  float4 gg = *(const float4*)(g + c);
  float4 bb = *(const float4*)(be + c);
  float4 y;
  y.x = (xv.x - mu) * rs * gg.x + bb.x;
  y.y = (xv.y - mu) * rs * gg.y + bb.y;
  y.z = (xv.z - mu) * rs * gg.z + bb.z;
  y.w = (xv.w - mu) * rs * gg.w + bb.w;
  if (outf) *(float4*)(outf + base + c) = y;
  if (outb) {
    bf16* o = outb + base + c;
    o[0] = __float2bfloat16(y.x);
    o[1] = __float2bfloat16(y.y);
    o[2] = __float2bfloat16(y.z);
    o[3] = __float2bfloat16(y.w);
  }
}

// ---------------------------------------------------------------------------
extern "C" void kernel_launch(void* const* d_in, const int* in_sizes, int n_in,
                              void* d_out, int out_size, void* d_ws,
                              size_t ws_size, hipStream_t stream) {
  const float* x    = (const float*)d_in[0];
  const float* mask = (const float*)d_in[1];
  const float* wq_w = (const float*)d_in[2];
  const float* wq_b = (const float*)d_in[3];
  const float* wk_w = (const float*)d_in[4];
  const float* wk_b = (const float*)d_in[5];
  const float* wv_w = (const float*)d_in[6];
  const float* wv_b = (const float*)d_in[7];
  const float* wo_w = (const float*)d_in[8];
  const float* wo_b = (const float*)d_in[9];
  const float* f1_w = (const float*)d_in[10];
  const float* f1_b = (const float*)d_in[11];
  const float* f2_w = (const float*)d_in[12];
  const float* f2_b = (const float*)d_in[13];
  const float* ln1_g = (const float*)d_in[14];
  const float* ln1_b = (const float*)d_in[15];
  const float* ln2_g = (const float*)d_in[16];
  const float* ln2_b = (const float*)d_in[17];
  float* out = (float*)d_out;

  char* ws = (char*)d_ws;
  const size_t MB = 1u << 20;
  // [0,8)   xbf -> attnb (dead after Wo)
  // [8,14)  W3T (dead after QKV)   [14,16) woT (dead after Wo)
  // [16,17) bqkv
  // [17,41) Qb/Kb/Vt (dead after attn) ; ffn1 = [17,49)
  // [49,57) f1T   [57,65) f2T
  // [65,97) proj partials (dead after ln1) -> f2 partials
  // [97,105) hbf                                  peak 105 MB
  bf16*  xbf   = (bf16*)(ws + 0 * MB);
  bf16*  W3T   = (bf16*)(ws + 8 * MB);
  bf16*  woT   = (bf16*)(ws + 14 * MB);
  float* bqkv  = (float*)(ws + 16 * MB);
  bf16*  Qb    = (bf16*)(ws + 17 * MB);
  bf16*  attnb = (bf16*)(ws + 0 * MB);
  bf16*  ffn1  = (bf16*)(ws + 17 * MB);
  bf16*  f1T   = (bf16*)(ws + 49 * MB);
  bf16*  f2T   = (bf16*)(ws + 57 * MB);
  float* parts = (float*)(ws + 65 * MB);   // 2 x 16 MB (proj, then f2)
  bf16*  hbf   = (bf16*)(ws + 97 * MB);
  const size_t PSTRIDE = (size_t)MTOT * E_DIM;   // elems per partial

  // pre-pass
  cvt_bf16<<<4096, 256, 0, stream>>>(x, xbf);
  transpose_all<<<dim3(32, 32, 12), 256, 0, stream>>>(
      wq_w, wk_w, wv_w, wo_w, f1_w, f2_w, W3T, woT, f1T, f2T);
  prep_bias<<<12, 256, 0, stream>>>(wq_b, wk_b, wv_b, bqkv);

  // fused QKV projection -> Qb (B*H,S,D), Kb, Vt (B*H,D,S)
  gemm_bt<<<dim3(32, 24, 1), 256, 0, stream>>>(xbf, W3T, bqkv, Qb,
                                               MTOT, 3 * E_DIM, E_DIM, E_DIM, 2);

  // attention
  flash_attn<<<dim3(S_LEN / 64, NB * NH), 256, 0, stream>>>(
      Qb, Qb + (1 << 22), Qb + (1 << 23), mask, attnb);

  // output projection, split-K=2 -> fp32 partials
  gemm_bt<<<dim3(32, 8, 2), 256, 0, stream>>>(attnb, woT, nullptr, parts,
                                              MTOT, E_DIM, E_DIM / 2, E_DIM, 0);

  // h = LN(p0+p1+wo_b + x) -> bf16 only
  ln_reduce<<<MTOT, 256, 0, stream>>>(parts, parts + PSTRIDE, x, nullptr,
                                      wo_b, ln1_g, ln1_b, nullptr, hbf);

  // FFN1: relu(h @ f1 + b) -> bf16
  gemm_bt<<<dim3(32, 32, 1), 256, 0, stream>>>(hbf, f1T, f1_b, ffn1,
                                               MTOT, FFN, E_DIM, E_DIM, 1);

  // FFN2, split-K=2 -> fp32 partials
  gemm_bt<<<dim3(32, 8, 2), 256, 0, stream>>>(ffn1, f2T, nullptr, parts,
                                              MTOT, E_DIM, FFN / 2, FFN, 0);

  // out = LN(p0+p1+f2_b + h)
  ln_reduce<<<MTOT, 256, 0, stream>>>(parts, parts + PSTRIDE, nullptr, hbf,
                                      f2_b, ln2_g, ln2_b, out, nullptr);
}